// Round 16
// baseline (161.750 us; speedup 1.0000x reference)
//
#include <hip/hip_runtime.h>
#include <stdint.h>

#define M_DIM 8192   // K of the Gram GEMM
#define N_DIM 4096   // output N x N

typedef __attribute__((ext_vector_type(4))) int i32x4;
typedef __attribute__((ext_vector_type(8))) int i32x8;
typedef __attribute__((ext_vector_type(16))) float f32x16;

// fp32 -> OCP e4m3 (RNE, FTZ below 2^-6, saturate to 448)
__device__ __forceinline__ unsigned char f2e4m3(float x) {
  union { float f; uint32_t u; } v;
  v.f = x;
  const uint32_t s = (v.u >> 24) & 0x80;
  const uint32_t au = v.u & 0x7fffffffu;
  if (au < 0x3c800000u) return (unsigned char)s;  // |x| < 2^-6 -> 0
  const uint32_t r = au + 0x7ffffu + ((au >> 20) & 1u);  // RNE at 3 mantissa bits
  int e = (int)(r >> 23) - 127;
  uint32_t m = (r >> 20) & 7u;
  if (e > 8 || (e == 8 && m == 7)) { e = 8; m = 6; }  // sat 448, avoid NaN
  return (unsigned char)(s | ((uint32_t)(e + 7) << 3) | m);
}

__device__ __forceinline__ void gl_lds16b(const char* g, char* l) {
  __builtin_amdgcn_global_load_lds(
      (const __attribute__((address_space(1))) void*)g,
      (__attribute__((address_space(3))) void*)l, 16, 0, 0);
}

#define CFENCE asm volatile("" ::: "memory")

// ---------------- Kernel 1: A[M][N] fp32 -> At packed operand-major fp8.
// At layout: [nblk(16)][kc(128)][g(8)][c(4)][r32(32)][byte e(16)]
//   element (n, k): nblk=n>>8, kc=k>>6, g=(n>>5)&7, c=(k>>4)&3, r32=n&31, e=k&15
// 16KB per (nblk,kc); every operand fragment is a contiguous 512B region.
__global__ __launch_bounds__(256) void transpose_pack_fp8(
    const float* __restrict__ A, unsigned char* __restrict__ At) {
  __shared__ unsigned char tile[64][68];  // tile[x][y] = A[m0+y][n0+x]
  const int bm = blockIdx.x % (M_DIM / 64);
  const int bn = blockIdx.x / (M_DIM / 64);
  const int m0 = bm * 64, n0 = bn * 64;
  const int t = threadIdx.x;
  const int tr = t >> 4;
  const int tc = (t & 15) << 2;
#pragma unroll
  for (int p = 0; p < 4; ++p) {
    const int r = p * 16 + tr;  // m_local
    const float4 v = *reinterpret_cast<const float4*>(
        &A[(size_t)(m0 + r) * N_DIM + (n0 + tc)]);
    tile[tc + 0][r] = f2e4m3(v.x);
    tile[tc + 1][r] = f2e4m3(v.y);
    tile[tc + 2][r] = f2e4m3(v.z);
    tile[tc + 3][r] = f2e4m3(v.w);
  }
  __syncthreads();
  const int cC = (tc >> 4) & 3;   // k-chunk within 64
  const int eC = tc & 15;         // byte within 16B chunk
  const int nblk = n0 >> 8;
  const int kc = m0 >> 6;
  unsigned char* const obase = At + ((size_t)(nblk * 128 + kc) * 8) * 2048;
#pragma unroll
  for (int p = 0; p < 4; ++p) {
    const int rn = p * 16 + tr;       // n_local
    const int n = n0 + rn;
    const int g = (n >> 5) & 7;
    const int r32 = n & 31;
    uchar4 o;
    o.x = tile[rn][tc + 0];  // k = m0+tc+0 .. +3
    o.y = tile[rn][tc + 1];
    o.z = tile[rn][tc + 2];
    o.w = tile[rn][tc + 3];
    *reinterpret_cast<uchar4*>(
        &obase[g * 2048 + cC * 512 + r32 * 16 + eC]) = o;
  }
}

// ---------------- Kernel 2: 256x256 tile, 8 waves (2x4, wave 128x64),
// MX-scaled mfma_scale_f32_32x32x64_f8f6f4 (unit scales).
// SPLIT-PATH OPERANDS: A via LDS (4 bufs x 16KB, gl_lds, stage S+3,
// 4-way wave reuse), B via direct global->VGPR dwordx4 (VMEM path,
// double-buffered regs, loaded 1 iter ahead). One barrier + counted
// vmcnt(2) per iter (FIFO: [B(S):4, A(S+2):2] at iter top).
__global__ __launch_bounds__(512, 1) void gram_fp8s(
    const unsigned char* __restrict__ At, float* __restrict__ C) {
  __shared__ char smem[65536];  // 4 x 16KB A buffers

  const int bid = (int)blockIdx.x;
  const int wg = (bid & 7) * 32 + (bid >> 3);  // XCD swizzle (256 % 8 == 0)
  const int bi = wg >> 4, bj = wg & 15;

  const int t = (int)threadIdx.x;
  const int lane = t & 63, wave = t >> 6;
  const int wr = wave >> 2, wc = wave & 3;   // wave tile: rows wr*128, cols wc*64
  const int l31 = lane & 31, hi = lane >> 5;

  // A operand read addresses in a 16KB buffer (contiguous 512B regions)
  int adA[4];
#pragma unroll
  for (int mb = 0; mb < 4; ++mb)
    adA[mb] = (wr * 4 + mb) * 2048 + hi * 1024 + l31 * 16;

  // B global operand base (per wave): block g = wc*2+nb, chunk halves 2hi,2hi+1
  const char* const Atb = (const char*)At;
  const char* const sAc = Atb + (size_t)bi * (128 * 16384);
  const char* const sBc = Atb + (size_t)bj * (128 * 16384);
  int adB[2];
#pragma unroll
  for (int nb = 0; nb < 2; ++nb)
    adB[nb] = (wc * 2 + nb) * 2048 + hi * 1024 + l31 * 16;

  const int dd = t * 16;  // 0..8176 (512 threads)

  i32x4 b0[2][2], b1[2][2];   // [set][nb][lo/hi] B register double-buffer
  f32x16 acc[4][2] = {};

  // prologue: stage A chunks 0,1,2 (2 gl_lds each); load B(0) into set 0
#pragma unroll
  for (int ss = 0; ss < 3; ++ss) {
    char* const b = smem + ss * 16384;
    const size_t ko = (size_t)ss * 16384;
    gl_lds16b(sAc + ko + dd, b + dd);
    gl_lds16b(sAc + ko + 8192 + dd, b + 8192 + dd);
  }
#pragma unroll
  for (int nb = 0; nb < 2; ++nb) {
    b0[nb][0] = *reinterpret_cast<const i32x4*>(sBc + adB[nb]);
    b0[nb][1] = *reinterpret_cast<const i32x4*>(sBc + adB[nb] + 512);
  }

// iter S: wait vmcnt; barrier; read A frags (buf S&3); issue B(S+1) loads
// (set NXT); stage A(S+3); MFMA with A frags + B set CUR.
#define ITER(S, BCUR, BNXT, STG, LDB, VMW) do {                              \
  if ((VMW) == 2)      asm volatile("s_waitcnt vmcnt(2)" ::: "memory");      \
  else if ((VMW) == 0) asm volatile("s_waitcnt vmcnt(0)" ::: "memory");      \
  __builtin_amdgcn_s_barrier();                                              \
  CFENCE;                                                                    \
  {                                                                          \
    const char* const bb = smem + ((S) & 3) * 16384;                         \
    i32x8 av[4];                                                             \
    _Pragma("unroll") for (int mb = 0; mb < 4; ++mb) {                       \
      const i32x4 lo = *reinterpret_cast<const i32x4*>(bb + adA[mb]);        \
      const i32x4 hv = *reinterpret_cast<const i32x4*>(bb + adA[mb] + 512);  \
      av[mb] = __builtin_shufflevector(lo, hv, 0, 1, 2, 3, 4, 5, 6, 7);      \
    }                                                                        \
    if (LDB) {                                                               \
      const char* const gb = sBc + (size_t)((S) + 1) * 16384;                \
      _Pragma("unroll") for (int nb = 0; nb < 2; ++nb) {                     \
        BNXT[nb][0] = *reinterpret_cast<const i32x4*>(gb + adB[nb]);         \
        BNXT[nb][1] = *reinterpret_cast<const i32x4*>(gb + adB[nb] + 512);   \
      }                                                                      \
    }                                                                        \
    if (STG) {                                                               \
      char* const sbf = smem + (((S) + 3) & 3) * 16384;                      \
      const size_t ko = (size_t)((S) + 3) * 16384;                           \
      gl_lds16b(sAc + ko + dd, sbf + dd);                                    \
      gl_lds16b(sAc + ko + 8192 + dd, sbf + 8192 + dd);                      \
    }                                                                        \
    _Pragma("unroll") for (int mb = 0; mb < 4; ++mb)                         \
      _Pragma("unroll") for (int nb = 0; nb < 2; ++nb) {                     \
        const i32x8 bv = __builtin_shufflevector(                            \
            BCUR[nb][0], BCUR[nb][1], 0, 1, 2, 3, 4, 5, 6, 7);               \
        acc[mb][nb] = __builtin_amdgcn_mfma_scale_f32_32x32x64_f8f6f4(       \
            av[mb], bv, acc[mb][nb], 0, 0,                                   \
            0, 0x7F7F7F7F, 0, 0x7F7F7F7F);                                   \
      }                                                                      \
  }                                                                          \
} while (0)

  // 128 K-chunks of 64; stage A(S+3) for S<=124, load B(S+1) for S<=126
  ITER(0, b0, b1, true, true, 0);
  ITER(1, b1, b0, true, true, 2);
  ITER(2, b0, b1, true, true, 2);
  ITER(3, b1, b0, true, true, 2);
  for (int s = 4; s < 124; s += 4) {
    ITER(s + 0, b0, b1, true, true, 2);
    ITER(s + 1, b1, b0, true, true, 2);
    ITER(s + 2, b0, b1, true, true, 2);
    ITER(s + 3, b1, b0, true, true, 2);
  }
  ITER(124, b0, b1, true, true, 2);   // stages A(127)
  ITER(125, b1, b0, false, true, 2);  // loads B(126)
  ITER(126, b0, b1, false, true, 0);  // loads B(127)
  ITER(127, b1, b0, false, false, 0);

#undef ITER

  // epilogue: 32x32 C/D map (verified R6/R9/R11): col = lane&31,
  // row = (reg&3) + 8*(reg>>2) + 4*(lane>>5)
  const int rb = bi * 256 + wr * 128;
  const int cb = bj * 256 + wc * 64;
#pragma unroll
  for (int mb = 0; mb < 4; ++mb) {
#pragma unroll
    for (int nb = 0; nb < 2; ++nb) {
      const int c = cb + nb * 32 + l31;
#pragma unroll
      for (int rg = 0; rg < 4; ++rg) {
        const int r0 = rb + mb * 32 + rg * 8 + hi * 4;
#pragma unroll
        for (int j = 0; j < 4; ++j)
          C[(size_t)(r0 + j) * N_DIM + c] = acc[mb][nb][rg * 4 + j];
      }
    }
  }
}

extern "C" void kernel_launch(void* const* d_in, const int* in_sizes, int n_in,
                              void* d_out, int out_size, void* d_ws, size_t ws_size,
                              hipStream_t stream) {
  const float* A = (const float*)d_in[0];
  float* C = (float*)d_out;
  unsigned char* At = (unsigned char*)d_ws;  // 32 MiB packed

  transpose_pack_fp8<<<dim3((M_DIM / 64) * (N_DIM / 64)), 256, 0, stream>>>(A, At);
  gram_fp8s<<<dim3(16 * 16), 512, 0, stream>>>(At, C);
}

// Round 17
// 138.272 us; speedup vs baseline: 1.1698x; 1.1698x over previous
//
#include <hip/hip_runtime.h>
#include <stdint.h>

#define M_DIM 8192   // K of the Gram GEMM
#define N_DIM 4096   // output N x N

typedef __attribute__((ext_vector_type(4))) int i32x4;
typedef __attribute__((ext_vector_type(8))) int i32x8;
typedef __attribute__((ext_vector_type(16))) float f32x16;

// fp32 -> OCP e4m3 (RNE, FTZ below 2^-6, saturate to 448)
__device__ __forceinline__ unsigned char f2e4m3(float x) {
  union { float f; uint32_t u; } v;
  v.f = x;
  const uint32_t s = (v.u >> 24) & 0x80;
  const uint32_t au = v.u & 0x7fffffffu;
  if (au < 0x3c800000u) return (unsigned char)s;  // |x| < 2^-6 -> 0
  const uint32_t r = au + 0x7ffffu + ((au >> 20) & 1u);  // RNE at 3 mantissa bits
  int e = (int)(r >> 23) - 127;
  uint32_t m = (r >> 20) & 7u;
  if (e > 8 || (e == 8 && m == 7)) { e = 8; m = 6; }  // sat 448, avoid NaN
  return (unsigned char)(s | ((uint32_t)(e + 7) << 3) | m);
}

__device__ __forceinline__ void gl_lds16b(const char* g, char* l) {
  __builtin_amdgcn_global_load_lds(
      (const __attribute__((address_space(1))) void*)g,
      (__attribute__((address_space(3))) void*)l, 16, 0, 0);
}

#define CFENCE asm volatile("" ::: "memory")

// ---------------- Kernel 1: A[M][N] fp32 -> At packed operand-major fp8.
// At layout: [nblk(16)][kc(128)][g(8)][c(4)][r32(32)][byte e(16)]
//   element (n, k): nblk=n>>8, kc=k>>6, g=(n>>5)&7, c=(k>>4)&3, r32=n&31, e=k&15
// Phase 2 rewritten for 16B/thread aligned stores (write coalescing).
__global__ __launch_bounds__(256) void transpose_pack_fp8(
    const float* __restrict__ A, unsigned char* __restrict__ At) {
  __shared__ unsigned char tile[64][68];  // tile[x][y] = fp8(A[m0+y][n0+x])
  const int bm = blockIdx.x % (M_DIM / 64);
  const int bn = blockIdx.x / (M_DIM / 64);
  const int m0 = bm * 64, n0 = bn * 64;
  const int t = threadIdx.x;
  const int tr = t >> 4;
  const int tc = (t & 15) << 2;
#pragma unroll
  for (int p = 0; p < 4; ++p) {
    const int r = p * 16 + tr;  // m_local
    const float4 v = *reinterpret_cast<const float4*>(
        &A[(size_t)(m0 + r) * N_DIM + (n0 + tc)]);
    tile[tc + 0][r] = f2e4m3(v.x);
    tile[tc + 1][r] = f2e4m3(v.y);
    tile[tc + 2][r] = f2e4m3(v.z);
    tile[tc + 3][r] = f2e4m3(v.w);
  }
  __syncthreads();
  // phase 2: thread t -> rn = t>>2 (n_local), kc = t&3 (16B k-chunk).
  // Reads 16 contiguous LDS bytes (2-way bank alias = free), emits ONE
  // aligned 16B store. Mapping identical to R11's byte-level layout.
  const int rn = t >> 2;
  const int kc = t & 3;
  const int n = n0 + rn;
  const int g = (n >> 5) & 7;
  const int r32 = n & 31;
  const int nblk = n0 >> 8;
  const int kcg = m0 >> 6;
  unsigned char* const obase = At + ((size_t)(nblk * 128 + kcg) * 8) * 2048;
  uint4 o;
  o.x = *reinterpret_cast<const uint32_t*>(&tile[rn][kc * 16 + 0]);
  o.y = *reinterpret_cast<const uint32_t*>(&tile[rn][kc * 16 + 4]);
  o.z = *reinterpret_cast<const uint32_t*>(&tile[rn][kc * 16 + 8]);
  o.w = *reinterpret_cast<const uint32_t*>(&tile[rn][kc * 16 + 12]);
  *reinterpret_cast<uint4*>(&obase[g * 2048 + kc * 512 + r32 * 16]) = o;
}

// ---------------- Kernel 2: R11 VERBATIM (proven 105 us, 0 conflicts).
// 256x256 tile, 8 waves (2x4, wave 128x64), MX-scaled
// mfma_scale_f32_32x32x64_f8f6f4 (unit scales 0x7F = 2^0, exact).
// 4 LDS bufs of 32KB (A-chunk 16KB @0, B-chunk @16384), stage S+3,
// vmcnt(8), one barrier/iter, order {reads -> STG -> MFMA}.
__global__ __launch_bounds__(512, 1) void gram_fp8s(
    const unsigned char* __restrict__ At, float* __restrict__ C) {
  __shared__ char smem[131072];

  const int bid = (int)blockIdx.x;
  const int wg = (bid & 7) * 32 + (bid >> 3);  // XCD swizzle (256 % 8 == 0)
  const int bi = wg >> 4, bj = wg & 15;

  const int t = (int)threadIdx.x;
  const int lane = t & 63, wave = t >> 6;
  const int wr = wave >> 2, wc = wave & 3;   // wave tile: rows wr*128, cols wc*64
  const int l31 = lane & 31, hi = lane >> 5;

  // operand read addresses: group block @ g*2048; chunks c = 2hi, 2hi+1
  int adA0[4], adB0[2];
#pragma unroll
  for (int mb = 0; mb < 4; ++mb)
    adA0[mb] = (wr * 4 + mb) * 2048 + hi * 1024 + l31 * 16;
#pragma unroll
  for (int nb = 0; nb < 2; ++nb)
    adB0[nb] = 16384 + (wc * 2 + nb) * 2048 + hi * 1024 + l31 * 16;

  // staging: plain linear 16KB copies (packed global layout == LDS layout)
  const char* const Atb = (const char*)At;
  const char* const sAc = Atb + (size_t)bi * (128 * 16384);
  const char* const sBc = Atb + (size_t)bj * (128 * 16384);
  const int dd = t * 16;  // 0..8176

  f32x16 acc[4][2] = {};

  // prologue: stage K-chunks 0,1,2 into bufs 0,1,2 (4 gl_lds each)
#pragma unroll
  for (int ss = 0; ss < 3; ++ss) {
    char* const b = smem + ss * 32768;
    const size_t ko = (size_t)ss * 16384;
    gl_lds16b(sAc + ko + dd, b + dd);
    gl_lds16b(sAc + ko + 8192 + dd, b + 8192 + dd);
    gl_lds16b(sBc + ko + dd, b + 16384 + dd);
    gl_lds16b(sBc + ko + 8192 + dd, b + 16384 + 8192 + dd);
  }

#define ITER(S, STG, VMW) do {                                               \
  if ((VMW) == 8)      asm volatile("s_waitcnt vmcnt(8)" ::: "memory");      \
  else if ((VMW) == 4) asm volatile("s_waitcnt vmcnt(4)" ::: "memory");      \
  else if ((VMW) == 0) asm volatile("s_waitcnt vmcnt(0)" ::: "memory");      \
  __builtin_amdgcn_s_barrier();                                              \
  CFENCE;                                                                    \
  {                                                                          \
    const char* const bb = smem + ((S) & 3) * 32768;                         \
    i32x8 av[4], bv[2];                                                      \
    _Pragma("unroll") for (int mb = 0; mb < 4; ++mb) {                       \
      const i32x4 lo = *reinterpret_cast<const i32x4*>(bb + adA0[mb]);       \
      const i32x4 hv = *reinterpret_cast<const i32x4*>(bb + adA0[mb] + 512); \
      av[mb] = __builtin_shufflevector(lo, hv, 0, 1, 2, 3, 4, 5, 6, 7);      \
    }                                                                        \
    _Pragma("unroll") for (int nb = 0; nb < 2; ++nb) {                       \
      const i32x4 lo = *reinterpret_cast<const i32x4*>(bb + adB0[nb]);       \
      const i32x4 hv = *reinterpret_cast<const i32x4*>(bb + adB0[nb] + 512); \
      bv[nb] = __builtin_shufflevector(lo, hv, 0, 1, 2, 3, 4, 5, 6, 7);      \
    }                                                                        \
    if (STG) {                                                               \
      char* const sbf = smem + (((S) + 3) & 3) * 32768;                      \
      const size_t ko = (size_t)((S) + 3) * 16384;                           \
      gl_lds16b(sAc + ko + dd, sbf + dd);                                    \
      gl_lds16b(sAc + ko + 8192 + dd, sbf + 8192 + dd);                      \
      gl_lds16b(sBc + ko + dd, sbf + 16384 + dd);                            \
      gl_lds16b(sBc + ko + 8192 + dd, sbf + 16384 + 8192 + dd);              \
    }                                                                        \
    _Pragma("unroll") for (int mb = 0; mb < 4; ++mb)                         \
      _Pragma("unroll") for (int nb = 0; nb < 2; ++nb)                       \
        acc[mb][nb] = __builtin_amdgcn_mfma_scale_f32_32x32x64_f8f6f4(       \
            av[mb], bv[nb], acc[mb][nb], 0, 0,                               \
            0, 0x7F7F7F7F, 0, 0x7F7F7F7F);                                   \
  }                                                                          \
} while (0)

  // 128 K-chunks of 64; stage chunk S+3 in iters 0..124
  for (int s = 0; s < 124; s += 4) {
    ITER(s + 0, true, 8);
    ITER(s + 1, true, 8);
    ITER(s + 2, true, 8);
    ITER(s + 3, true, 8);
  }
  ITER(124, true, 8);    // stages chunk 127
  ITER(125, false, 8);
  ITER(126, false, 4);
  ITER(127, false, 0);

#undef ITER

  // epilogue: 32x32 C/D map (verified R6/R9/R11): col = lane&31,
  // row = (reg&3) + 8*(reg>>2) + 4*(lane>>5)
  const int rb = bi * 256 + wr * 128;
  const int cb = bj * 256 + wc * 64;
#pragma unroll
  for (int mb = 0; mb < 4; ++mb) {
#pragma unroll
    for (int nb = 0; nb < 2; ++nb) {
      const int c = cb + nb * 32 + l31;
#pragma unroll
      for (int rg = 0; rg < 4; ++rg) {
        const int r0 = rb + mb * 32 + rg * 8 + hi * 4;
#pragma unroll
        for (int j = 0; j < 4; ++j)
          C[(size_t)(r0 + j) * N_DIM + c] = acc[mb][nb][rg * 4 + j];
      }
    }
  }
}

extern "C" void kernel_launch(void* const* d_in, const int* in_sizes, int n_in,
                              void* d_out, int out_size, void* d_ws, size_t ws_size,
                              hipStream_t stream) {
  const float* A = (const float*)d_in[0];
  float* C = (float*)d_out;
  unsigned char* At = (unsigned char*)d_ws;  // 32 MiB packed

  transpose_pack_fp8<<<dim3((M_DIM / 64) * (N_DIM / 64)), 256, 0, stream>>>(A, At);
  gram_fp8s<<<dim3(16 * 16), 512, 0, stream>>>(At, C);
}

// Round 19
// 133.276 us; speedup vs baseline: 1.2136x; 1.0375x over previous
//
#include <hip/hip_runtime.h>
#include <stdint.h>

#define M_DIM 8192   // K of the Gram GEMM
#define N_DIM 4096   // output N x N

typedef __attribute__((ext_vector_type(2))) int i32x2;
typedef __attribute__((ext_vector_type(8))) int i32x8;
typedef __attribute__((ext_vector_type(16))) float f32x16;

// fp32 -> fp6 e2m3 code (6 bits), RNE on the e2m3 grid, unit scale.
__device__ __forceinline__ uint32_t f2e2m3(float x) {
  const uint32_t s = (__float_as_uint(x) >> 26) & 0x20;  // sign -> bit 5
  float v = fabsf(x);
  v = fminf(v, 7.5f);
  const float rstep = v < 2.f ? 8.f : (v < 4.f ? 4.f : 2.f);
  const float q = rintf(v * rstep) / rstep;  // RNE on grid
  uint32_t bits;
  if (q < 1.f) {
    bits = (uint32_t)(q * 8.f);              // subnormal: 0..7
  } else {
    const uint32_t u = __float_as_uint(q);
    const uint32_t ef = ((u >> 23) - 127) + 1;  // 1..3
    bits = (ef << 3) | ((u >> 20) & 7);
  }
  return bits | s;
}

// 4B/lane async global->LDS (the MEASURED-good width, m03)
__device__ __forceinline__ void gl_lds4b(const char* g, char* l) {
  __builtin_amdgcn_global_load_lds(
      (const __attribute__((address_space(1))) void*)g,
      (__attribute__((address_space(3))) void*)l, 4, 0, 0);
}

#define CFENCE asm volatile("" ::: "memory")

// ---------------- Kernel 1: A[M][N] fp32 -> At packed fp6 e2m3 (R18 verbatim).
// At layout: [nblk(16)][kc(128)][g(8)][hi(2)][r32(32)][24B]
//   element (n,k): nblk=n>>8, kc=k>>6, g=(n>>5)&7, hi=(k>>5)&1, r32=n&31,
//   e=k&31 -> bits [6e+5:6e] of the 24B field (dense little-endian).
__global__ __launch_bounds__(256) void transpose_pack_fp6(
    const float* __restrict__ A, unsigned char* __restrict__ At) {
  __shared__ float tile[64][68];  // tile[n_local][m_local] raw floats
  const int bm = blockIdx.x % (M_DIM / 64);
  const int bn = blockIdx.x / (M_DIM / 64);
  const int m0 = bm * 64, n0 = bn * 64;
  const int t = threadIdx.x;
  const int tr = t >> 4;
  const int tc = (t & 15) << 2;
#pragma unroll
  for (int p = 0; p < 4; ++p) {
    const int r = p * 16 + tr;  // m_local
    const float4 v = *reinterpret_cast<const float4*>(
        &A[(size_t)(m0 + r) * N_DIM + (n0 + tc)]);
    tile[tc + 0][r] = v.x;
    tile[tc + 1][r] = v.y;
    tile[tc + 2][r] = v.z;
    tile[tc + 3][r] = v.w;
  }
  __syncthreads();
  if (t < 128) {
    const int rn = t >> 1;      // n_local
    const int hi = t & 1;       // k-half (32 elements)
    uint32_t out[6] = {0, 0, 0, 0, 0, 0};
#pragma unroll
    for (int e = 0; e < 32; ++e) {
      const uint32_t c = f2e2m3(tile[rn][hi * 32 + e]);
      const int p = 6 * e;
      out[p >> 5] |= c << (p & 31);
      if ((p & 31) > 26) out[(p >> 5) + 1] |= c >> (32 - (p & 31));
    }
    const int n = n0 + rn;
    const int g = (n >> 5) & 7;
    const int r32 = n & 31;
    unsigned char* const base =
        At + ((size_t)((n0 >> 8) * 128 + (m0 >> 6))) * 12288 +
        g * 1536 + hi * 768 + r32 * 24;
    uint2* const o = reinterpret_cast<uint2*>(base);  // 8B-aligned
    o[0] = make_uint2(out[0], out[1]);
    o[1] = make_uint2(out[2], out[3]);
    o[2] = make_uint2(out[4], out[5]);
  }
}

// ---------------- Kernel 2: R18 schedule, staging width 12 -> 4 (the ONLY
// change). fp6 e2m3 via mfma_scale_f32_32x32x64_f8f6f4, cbsz=blgp=2, unit
// scales. 4 LDS bufs of 24576B (A 12288 @0, B @12288), stage S+3
// (12 x gl_lds4 per chunk), vmcnt(24)/12/0 ladder, one barrier/iter.
__global__ __launch_bounds__(512, 1) void gram_fp6(
    const unsigned char* __restrict__ At, float* __restrict__ C) {
  __shared__ char smem[98304];  // 4 x 24576

  const int bid = (int)blockIdx.x;
  const int wg = (bid & 7) * 32 + (bid >> 3);  // XCD swizzle (256 % 8 == 0)
  const int bi = wg >> 4, bj = wg & 15;

  const int t = (int)threadIdx.x;
  const int lane = t & 63, wave = t >> 6;
  const int wr = wave >> 2, wc = wave & 3;   // wave tile: rows wr*128, cols wc*64
  const int l31 = lane & 31, hi = lane >> 5;

  // operand read addresses: field @ g*1536 + hi*768 + l31*24
  int adA[4], adB[2];
#pragma unroll
  for (int mb = 0; mb < 4; ++mb)
    adA[mb] = (wr * 4 + mb) * 1536 + hi * 768 + l31 * 24;
#pragma unroll
  for (int nb = 0; nb < 2; ++nb)
    adB[nb] = 12288 + (wc * 2 + nb) * 1536 + hi * 768 + l31 * 24;

  // staging: plain linear copies, 4B/lane x 512 threads = 2048B/instr,
  // 6 instrs per 12288B operand region, 12 per chunk.
  const char* const Atb = (const char*)At;
  const char* const sAc = Atb + (size_t)bi * (128 * 12288);
  const char* const sBc = Atb + (size_t)bj * (128 * 12288);
  const int dd = t * 4;  // 0..2044

  f32x16 acc[4][2] = {};

  // prologue: stage K-chunks 0,1,2 into bufs 0,1,2 (12 gl_lds4 each)
#pragma unroll
  for (int ss = 0; ss < 3; ++ss) {
    char* const b = smem + ss * 24576;
    const size_t ko = (size_t)ss * 12288;
#pragma unroll
    for (int i = 0; i < 6; ++i) {
      gl_lds4b(sAc + ko + i * 2048 + dd, b + i * 2048 + dd);
      gl_lds4b(sBc + ko + i * 2048 + dd, b + 12288 + i * 2048 + dd);
    }
  }

#define LOAD6(DST, BB, AD)                                                   \
  {                                                                          \
    const i32x2 q0 = *reinterpret_cast<const i32x2*>((BB) + (AD));           \
    const i32x2 q1 = *reinterpret_cast<const i32x2*>((BB) + (AD) + 8);       \
    const i32x2 q2 = *reinterpret_cast<const i32x2*>((BB) + (AD) + 16);      \
    DST[0] = q0[0]; DST[1] = q0[1]; DST[2] = q1[0]; DST[3] = q1[1];          \
    DST[4] = q2[0]; DST[5] = q2[1]; DST[6] = 0; DST[7] = 0;                  \
  }

#define ITER(S, STG, VMW) do {                                               \
  if ((VMW) == 24)      asm volatile("s_waitcnt vmcnt(24)" ::: "memory");    \
  else if ((VMW) == 12) asm volatile("s_waitcnt vmcnt(12)" ::: "memory");    \
  else if ((VMW) == 0)  asm volatile("s_waitcnt vmcnt(0)" ::: "memory");     \
  __builtin_amdgcn_s_barrier();                                              \
  CFENCE;                                                                    \
  {                                                                          \
    const char* const bb = smem + ((S) & 3) * 24576;                         \
    i32x8 av[4], bv[2];                                                      \
    _Pragma("unroll") for (int mb = 0; mb < 4; ++mb) LOAD6(av[mb], bb, adA[mb]) \
    _Pragma("unroll") for (int nb = 0; nb < 2; ++nb) LOAD6(bv[nb], bb, adB[nb]) \
    if (STG) {                                                               \
      char* const sbf = smem + (((S) + 3) & 3) * 24576;                      \
      const size_t ko = (size_t)((S) + 3) * 12288;                           \
      _Pragma("unroll") for (int i = 0; i < 6; ++i) {                        \
        gl_lds4b(sAc + ko + i * 2048 + dd, sbf + i * 2048 + dd);             \
        gl_lds4b(sBc + ko + i * 2048 + dd, sbf + 12288 + i * 2048 + dd);     \
      }                                                                      \
    }                                                                        \
    _Pragma("unroll") for (int mb = 0; mb < 4; ++mb)                         \
      _Pragma("unroll") for (int nb = 0; nb < 2; ++nb)                       \
        acc[mb][nb] = __builtin_amdgcn_mfma_scale_f32_32x32x64_f8f6f4(       \
            av[mb], bv[nb], acc[mb][nb], 2 /*FP6*/, 2 /*FP6*/,               \
            0, 0x7F7F7F7F, 0, 0x7F7F7F7F);                                   \
  }                                                                          \
} while (0)

  // 128 K-chunks of 64; stage chunk S+3 in iters 0..124
  for (int s = 0; s < 124; s += 4) {
    ITER(s + 0, true, 24);
    ITER(s + 1, true, 24);
    ITER(s + 2, true, 24);
    ITER(s + 3, true, 24);
  }
  ITER(124, true, 24);    // stages chunk 127
  ITER(125, false, 24);
  ITER(126, false, 12);
  ITER(127, false, 0);

#undef ITER
#undef LOAD6

  // epilogue: 32x32 C/D map (verified R6/R9/R11): col = lane&31,
  // row = (reg&3) + 8*(reg>>2) + 4*(lane>>5)
  const int rb = bi * 256 + wr * 128;
  const int cb = bj * 256 + wc * 64;
#pragma unroll
  for (int mb = 0; mb < 4; ++mb) {
#pragma unroll
    for (int nb = 0; nb < 2; ++nb) {
      const int c = cb + nb * 32 + l31;
#pragma unroll
      for (int rg = 0; rg < 4; ++rg) {
        const int r0 = rb + mb * 32 + rg * 8 + hi * 4;
#pragma unroll
        for (int j = 0; j < 4; ++j)
          C[(size_t)(r0 + j) * N_DIM + c] = acc[mb][nb][rg * 4 + j];
      }
    }
  }
}

extern "C" void kernel_launch(void* const* d_in, const int* in_sizes, int n_in,
                              void* d_out, int out_size, void* d_ws, size_t ws_size,
                              hipStream_t stream) {
  const float* A = (const float*)d_in[0];
  float* C = (float*)d_out;
  unsigned char* At = (unsigned char*)d_ws;  // 24 MiB packed fp6

  transpose_pack_fp6<<<dim3((M_DIM / 64) * (N_DIM / 64)), 256, 0, stream>>>(A, At);
  gram_fp6<<<dim3(16 * 16), 512, 0, stream>>>(At, C);
}

// Round 20
// 124.012 us; speedup vs baseline: 1.3043x; 1.0747x over previous
//
#include <hip/hip_runtime.h>
#include <stdint.h>

#define M_DIM 8192   // K of the Gram GEMM
#define N_DIM 4096   // output N x N

typedef __attribute__((ext_vector_type(2))) int i32x2;
typedef __attribute__((ext_vector_type(4))) int i32x4;
typedef __attribute__((ext_vector_type(8))) int i32x8;
typedef __attribute__((ext_vector_type(16))) float f32x16;

// fp32 -> fp6 e2m3 code (6 bits), RNE on the e2m3 grid, unit scale.
__device__ __forceinline__ uint32_t f2e2m3(float x) {
  const uint32_t s = (__float_as_uint(x) >> 26) & 0x20;  // sign -> bit 5
  float v = fabsf(x);
  v = fminf(v, 7.5f);
  const float rstep = v < 2.f ? 8.f : (v < 4.f ? 4.f : 2.f);
  const float q = rintf(v * rstep) / rstep;  // RNE on grid
  uint32_t bits;
  if (q < 1.f) {
    bits = (uint32_t)(q * 8.f);              // subnormal: 0..7
  } else {
    const uint32_t u = __float_as_uint(q);
    const uint32_t ef = ((u >> 23) - 127) + 1;  // 1..3
    bits = (ef << 3) | ((u >> 20) & 7);
  }
  return bits | s;
}

// 16B/lane async global->LDS (measured-good width; size=12 is BROKEN, R18/R19)
__device__ __forceinline__ void gl_lds16b(const char* g, char* l) {
  __builtin_amdgcn_global_load_lds(
      (const __attribute__((address_space(1))) void*)g,
      (__attribute__((address_space(3))) void*)l, 16, 0, 0);
}

#define CFENCE asm volatile("" ::: "memory")

// ---------------- Kernel 1: A[M][N] fp32 -> At packed fp6 e2m3, SPLIT-PLANE.
// Chunk (nblk,kc) = 16384 B (12288 payload + 4096 pad for 16B staging).
// Field (g,hi) = 768 B @ g*1536 + hi*768:
//   plane0 @ +0:   32 lanes x 16B  (dwords 0-3 of the lane's 24B fp6 field)
//   plane1 @ +512: 32 lanes x 8B   (dwords 4-5)
// element (n,k): nblk=n>>8, kc=k>>6, g=(n>>5)&7, hi=(k>>5)&1, r32=n&31,
//   e=k&31 -> bits [6e+5:6e] of the lane's dense 24B (R19-verified numerics).
__global__ __launch_bounds__(256) void transpose_pack_fp6(
    const float* __restrict__ A, unsigned char* __restrict__ At) {
  __shared__ float tile[64][68];  // tile[n_local][m_local] raw floats
  const int bm = blockIdx.x % (M_DIM / 64);
  const int bn = blockIdx.x / (M_DIM / 64);
  const int m0 = bm * 64, n0 = bn * 64;
  const int t = threadIdx.x;
  const int tr = t >> 4;
  const int tc = (t & 15) << 2;
#pragma unroll
  for (int p = 0; p < 4; ++p) {
    const int r = p * 16 + tr;  // m_local
    const float4 v = *reinterpret_cast<const float4*>(
        &A[(size_t)(m0 + r) * N_DIM + (n0 + tc)]);
    tile[tc + 0][r] = v.x;
    tile[tc + 1][r] = v.y;
    tile[tc + 2][r] = v.z;
    tile[tc + 3][r] = v.w;
  }
  __syncthreads();
  if (t < 128) {
    const int rn = t >> 1;      // n_local
    const int hi = t & 1;       // k-half (32 elements)
    uint32_t out[6] = {0, 0, 0, 0, 0, 0};
#pragma unroll
    for (int e = 0; e < 32; ++e) {
      const uint32_t c = f2e2m3(tile[rn][hi * 32 + e]);
      const int p = 6 * e;
      out[p >> 5] |= c << (p & 31);
      if ((p & 31) > 26) out[(p >> 5) + 1] |= c >> (32 - (p & 31));
    }
    const int n = n0 + rn;
    const int g = (n >> 5) & 7;
    const int r32 = n & 31;
    unsigned char* const fbase =
        At + ((size_t)((n0 >> 8) * 128 + (m0 >> 6))) * 16384 +
        g * 1536 + hi * 768;
    *reinterpret_cast<uint4*>(fbase + r32 * 16) =
        make_uint4(out[0], out[1], out[2], out[3]);
    *reinterpret_cast<uint2*>(fbase + 512 + r32 * 8) =
        make_uint2(out[4], out[5]);
  }
}

// ---------------- Kernel 2: R11 schedule verbatim; fp6 e2m3 split-plane.
// 256x256 tile, 8 waves (2x4, wave 128x64), mfma_scale_f32_32x32x64_f8f6f4
// cbsz=blgp=2 (FP6), unit scales. 4 LDS bufs of 32KB (A 16384 @0, B @16384),
// stage S+3 (4 x gl_lds16/thread/iter), vmcnt(8)/4/0, one barrier/iter.
// Operand read = 1 b128 (plane0) + 1 b64 (plane1): 192 read-instrs/iter
// (was 288 b64 in R19) -> read cost ~864 cyc, MFMA pipe 563.
__global__ __launch_bounds__(512, 1) void gram_fp6(
    const unsigned char* __restrict__ At, float* __restrict__ C) {
  __shared__ char smem[131072];  // 4 x 32768

  const int bid = (int)blockIdx.x;
  const int wg = (bid & 7) * 32 + (bid >> 3);  // XCD swizzle (256 % 8 == 0)
  const int bi = wg >> 4, bj = wg & 15;

  const int t = (int)threadIdx.x;
  const int lane = t & 63, wave = t >> 6;
  const int wr = wave >> 2, wc = wave & 3;   // wave tile: rows wr*128, cols wc*64
  const int l31 = lane & 31, hi = lane >> 5;

  // operand read addresses: field @ g*1536 + hi*768; planes @ +l31*16, +512+l31*8
  int adA0[4], adA1[4], adB0[2], adB1[2];
#pragma unroll
  for (int mb = 0; mb < 4; ++mb) {
    const int f = (wr * 4 + mb) * 1536 + hi * 768;
    adA0[mb] = f + l31 * 16;
    adA1[mb] = f + 512 + l31 * 8;
  }
#pragma unroll
  for (int nb = 0; nb < 2; ++nb) {
    const int f = 16384 + (wc * 2 + nb) * 1536 + hi * 768;
    adB0[nb] = f + l31 * 16;
    adB1[nb] = f + 512 + l31 * 8;
  }

  // staging: plain linear 16384B copies (2 x gl_lds16 per operand region)
  const char* const Atb = (const char*)At;
  const char* const sAc = Atb + (size_t)bi * (128 * 16384);
  const char* const sBc = Atb + (size_t)bj * (128 * 16384);
  const int dd = t * 16;  // 0..8176

  f32x16 acc[4][2] = {};

  // prologue: stage K-chunks 0,1,2 into bufs 0,1,2 (4 gl_lds16 each)
#pragma unroll
  for (int ss = 0; ss < 3; ++ss) {
    char* const b = smem + ss * 32768;
    const size_t ko = (size_t)ss * 16384;
    gl_lds16b(sAc + ko + dd, b + dd);
    gl_lds16b(sAc + ko + 8192 + dd, b + 8192 + dd);
    gl_lds16b(sBc + ko + dd, b + 16384 + dd);
    gl_lds16b(sBc + ko + 8192 + dd, b + 16384 + 8192 + dd);
  }

#define LOAD6(DST, BB, AD128, AD64)                                          \
  {                                                                          \
    const i32x4 q0 = *reinterpret_cast<const i32x4*>((BB) + (AD128));        \
    const i32x2 q1 = *reinterpret_cast<const i32x2*>((BB) + (AD64));         \
    DST[0] = q0[0]; DST[1] = q0[1]; DST[2] = q0[2]; DST[3] = q0[3];          \
    DST[4] = q1[0]; DST[5] = q1[1]; DST[6] = 0; DST[7] = 0;                  \
  }

#define ITER(S, STG, VMW) do {                                               \
  if ((VMW) == 8)      asm volatile("s_waitcnt vmcnt(8)" ::: "memory");      \
  else if ((VMW) == 4) asm volatile("s_waitcnt vmcnt(4)" ::: "memory");      \
  else if ((VMW) == 0) asm volatile("s_waitcnt vmcnt(0)" ::: "memory");      \
  __builtin_amdgcn_s_barrier();                                              \
  CFENCE;                                                                    \
  {                                                                          \
    const char* const bb = smem + ((S) & 3) * 32768;                         \
    i32x8 av[4], bv[2];                                                      \
    _Pragma("unroll") for (int mb = 0; mb < 4; ++mb)                         \
      LOAD6(av[mb], bb, adA0[mb], adA1[mb])                                  \
    _Pragma("unroll") for (int nb = 0; nb < 2; ++nb)                         \
      LOAD6(bv[nb], bb, adB0[nb], adB1[nb])                                  \
    if (STG) {                                                               \
      char* const sbf = smem + (((S) + 3) & 3) * 32768;                      \
      const size_t ko = (size_t)((S) + 3) * 16384;                           \
      gl_lds16b(sAc + ko + dd, sbf + dd);                                    \
      gl_lds16b(sAc + ko + 8192 + dd, sbf + 8192 + dd);                      \
      gl_lds16b(sBc + ko + dd, sbf + 16384 + dd);                            \
      gl_lds16b(sBc + ko + 8192 + dd, sbf + 16384 + 8192 + dd);              \
    }                                                                        \
    _Pragma("unroll") for (int mb = 0; mb < 4; ++mb)                         \
      _Pragma("unroll") for (int nb = 0; nb < 2; ++nb)                       \
        acc[mb][nb] = __builtin_amdgcn_mfma_scale_f32_32x32x64_f8f6f4(       \
            av[mb], bv[nb], acc[mb][nb], 2 /*FP6*/, 2 /*FP6*/,               \
            0, 0x7F7F7F7F, 0, 0x7F7F7F7F);                                   \
  }                                                                          \
} while (0)

  // 128 K-chunks of 64; stage chunk S+3 in iters 0..124
  for (int s = 0; s < 124; s += 4) {
    ITER(s + 0, true, 8);
    ITER(s + 1, true, 8);
    ITER(s + 2, true, 8);
    ITER(s + 3, true, 8);
  }
  ITER(124, true, 8);    // stages chunk 127
  ITER(125, false, 8);
  ITER(126, false, 4);
  ITER(127, false, 0);

#undef ITER
#undef LOAD6

  // epilogue: 32x32 C/D map (verified R6/R9/R11): col = lane&31,
  // row = (reg&3) + 8*(reg>>2) + 4*(lane>>5)
  const int rb = bi * 256 + wr * 128;
  const int cb = bj * 256 + wc * 64;
#pragma unroll
  for (int mb = 0; mb < 4; ++mb) {
#pragma unroll
    for (int nb = 0; nb < 2; ++nb) {
      const int c = cb + nb * 32 + l31;
#pragma unroll
      for (int rg = 0; rg < 4; ++rg) {
        const int r0 = rb + mb * 32 + rg * 8 + hi * 4;
#pragma unroll
        for (int j = 0; j < 4; ++j)
          C[(size_t)(r0 + j) * N_DIM + c] = acc[mb][nb][rg * 4 + j];
      }
    }
  }
}

extern "C" void kernel_launch(void* const* d_in, const int* in_sizes, int n_in,
                              void* d_out, int out_size, void* d_ws, size_t ws_size,
                              hipStream_t stream) {
  const float* A = (const float*)d_in[0];
  float* C = (float*)d_out;
  unsigned char* At = (unsigned char*)d_ws;  // 32 MiB (16KB-padded fp6 chunks)

  transpose_pack_fp6<<<dim3((M_DIM / 64) * (N_DIM / 64)), 256, 0, stream>>>(A, At);
  gram_fp6<<<dim3(16 * 16), 512, 0, stream>>>(At, C);
}

// Round 21
// 119.772 us; speedup vs baseline: 1.3505x; 1.0354x over previous
//
#include <hip/hip_runtime.h>
#include <stdint.h>

#define M_DIM 8192   // K of the Gram GEMM
#define N_DIM 4096   // output N x N

typedef __attribute__((ext_vector_type(2))) int i32x2;
typedef __attribute__((ext_vector_type(4))) int i32x4;
typedef __attribute__((ext_vector_type(8))) int i32x8;
typedef __attribute__((ext_vector_type(16))) float f32x16;

// fp32 -> fp6 e2m3 code (6 bits), RNE on the e2m3 grid, unit scale.
__device__ __forceinline__ uint32_t f2e2m3(float x) {
  const uint32_t s = (__float_as_uint(x) >> 26) & 0x20;  // sign -> bit 5
  float v = fabsf(x);
  v = fminf(v, 7.5f);
  const float rstep = v < 2.f ? 8.f : (v < 4.f ? 4.f : 2.f);
  const float q = rintf(v * rstep) / rstep;  // RNE on grid
  uint32_t bits;
  if (q < 1.f) {
    bits = (uint32_t)(q * 8.f);              // subnormal: 0..7
  } else {
    const uint32_t u = __float_as_uint(q);
    const uint32_t ef = ((u >> 23) - 127) + 1;  // 1..3
    bits = (ef << 3) | ((u >> 20) & 7);
  }
  return bits | s;
}

// 16B/lane async global->LDS (size=12 is BROKEN on gfx950 — R18/R19 evidence)
__device__ __forceinline__ void gl_lds16b(const char* g, char* l) {
  __builtin_amdgcn_global_load_lds(
      (const __attribute__((address_space(1))) void*)g,
      (__attribute__((address_space(3))) void*)l, 16, 0, 0);
}

#define CFENCE asm volatile("" ::: "memory")

// ---------------- Kernel 1: A[M][N] fp32 -> At packed fp6 e2m3, SPLIT-PLANE.
// Chunk (nblk,kc) = 16384 B (12288 payload + 4096 pad). Field (g,hi) = 768 B:
//   plane0 @ +0:   32 lanes x 16B (dwords 0-3 of lane's 24B fp6 field)
//   plane1 @ +512: 32 lanes x 8B  (dwords 4-5)
// All 256 threads pack: t -> rn=t>>2, hi=(t>>1)&1, half=t&1 (16 elems, 96 bits
// = dwords 3*half..3*half+2 of the field -> clean half split).
__global__ __launch_bounds__(256) void transpose_pack_fp6(
    const float* __restrict__ A, unsigned char* __restrict__ At) {
  __shared__ float tile[64][68];  // tile[n_local][m_local] raw floats
  const int bm = blockIdx.x % (M_DIM / 64);
  const int bn = blockIdx.x / (M_DIM / 64);
  const int m0 = bm * 64, n0 = bn * 64;
  const int t = threadIdx.x;
  const int tr = t >> 4;
  const int tc = (t & 15) << 2;
#pragma unroll
  for (int p = 0; p < 4; ++p) {
    const int r = p * 16 + tr;  // m_local
    const float4 v = *reinterpret_cast<const float4*>(
        &A[(size_t)(m0 + r) * N_DIM + (n0 + tc)]);
    tile[tc + 0][r] = v.x;
    tile[tc + 1][r] = v.y;
    tile[tc + 2][r] = v.z;
    tile[tc + 3][r] = v.w;
  }
  __syncthreads();
  {
    const int rn = t >> 2;        // n_local
    const int hi = (t >> 1) & 1;  // k-half (32 elems)
    const int half = t & 1;       // 16-elem half of the field
    const int kb = hi * 32 + half * 16;
    uint32_t out[3] = {0, 0, 0};
#pragma unroll
    for (int j = 0; j < 16; ++j) {
      const uint32_t c = f2e2m3(tile[rn][kb + j]);
      const int p = 6 * j;  // bit pos within this 96-bit half
      out[p >> 5] |= c << (p & 31);
      if ((p & 31) > 26) out[(p >> 5) + 1] |= c >> (32 - (p & 31));
    }
    const int n = n0 + rn;
    const int g = (n >> 5) & 7;
    const int r32 = n & 31;
    unsigned char* const fbase =
        At + ((size_t)((n0 >> 8) * 128 + (m0 >> 6))) * 16384 +
        g * 1536 + hi * 768;
    if (half == 0) {  // dwords 0,1,2 -> plane0 bytes 0..11
      *reinterpret_cast<uint2*>(fbase + r32 * 16) = make_uint2(out[0], out[1]);
      *reinterpret_cast<uint32_t*>(fbase + r32 * 16 + 8) = out[2];
    } else {          // dwords 3,4,5 -> plane0 byte 12, plane1 8B
      *reinterpret_cast<uint32_t*>(fbase + r32 * 16 + 12) = out[0];
      *reinterpret_cast<uint2*>(fbase + 512 + r32 * 8) = make_uint2(out[1], out[2]);
    }
  }
}

// ---------------- Kernel 2: 256x256 tile, 4 waves (2x2, wave 128x128) ->
// LDS reads 48KB/iter (8-wave was 72KB). fp6 e2m3 split-plane,
// mfma_scale_f32_32x32x64_f8f6f4 cbsz=blgp=2, unit scales. 4 LDS bufs of
// 32KB, stage S+3 (8 x gl_lds16/thread/iter @ 256 thr), vmcnt(16)/8/0,
// one barrier/iter. Operand read = b128 (plane0) + b64 (plane1).
__global__ __launch_bounds__(256, 1) void gram_fp6(
    const unsigned char* __restrict__ At, float* __restrict__ C) {
  __shared__ char smem[131072];  // 4 x 32768

  const int bid = (int)blockIdx.x;
  const int wg = (bid & 7) * 32 + (bid >> 3);  // XCD swizzle (256 % 8 == 0)
  const int bi = wg >> 4, bj = wg & 15;

  const int t = (int)threadIdx.x;
  const int lane = t & 63, wave = t >> 6;      // 4 waves
  const int wr = wave >> 1, wc = wave & 1;     // wave tile 128x128
  const int l31 = lane & 31, hi = lane >> 5;

  // operand read addresses: field @ g*1536 + hi*768; planes @ +l31*16, +512+l31*8
  int adA0[4], adA1[4], adB0[4], adB1[4];
#pragma unroll
  for (int mb = 0; mb < 4; ++mb) {
    const int f = (wr * 4 + mb) * 1536 + hi * 768;
    adA0[mb] = f + l31 * 16;
    adA1[mb] = f + 512 + l31 * 8;
  }
#pragma unroll
  for (int nb = 0; nb < 4; ++nb) {
    const int f = 16384 + (wc * 4 + nb) * 1536 + hi * 768;
    adB0[nb] = f + l31 * 16;
    adB1[nb] = f + 512 + l31 * 8;
  }

  // staging: plain linear 16384B copies; 256 thr x 16B = 4096B/instr, 4/matrix
  const char* const Atb = (const char*)At;
  const char* const sAc = Atb + (size_t)bi * (128 * 16384);
  const char* const sBc = Atb + (size_t)bj * (128 * 16384);
  const int dd = t * 16;  // 0..4080

  f32x16 acc[4][4] = {};

  // prologue: stage K-chunks 0,1,2 into bufs 0,1,2 (8 gl_lds16 each)
#pragma unroll
  for (int ss = 0; ss < 3; ++ss) {
    char* const b = smem + ss * 32768;
    const size_t ko = (size_t)ss * 16384;
#pragma unroll
    for (int i = 0; i < 4; ++i) {
      gl_lds16b(sAc + ko + i * 4096 + dd, b + i * 4096 + dd);
      gl_lds16b(sBc + ko + i * 4096 + dd, b + 16384 + i * 4096 + dd);
    }
  }

#define LOAD6(DST, BB, AD128, AD64)                                          \
  {                                                                          \
    const i32x4 q0 = *reinterpret_cast<const i32x4*>((BB) + (AD128));        \
    const i32x2 q1 = *reinterpret_cast<const i32x2*>((BB) + (AD64));         \
    DST[0] = q0[0]; DST[1] = q0[1]; DST[2] = q0[2]; DST[3] = q0[3];          \
    DST[4] = q1[0]; DST[5] = q1[1]; DST[6] = 0; DST[7] = 0;                  \
  }

#define ITER(S, STG, VMW) do {                                               \
  if ((VMW) == 16)     asm volatile("s_waitcnt vmcnt(16)" ::: "memory");     \
  else if ((VMW) == 8) asm volatile("s_waitcnt vmcnt(8)" ::: "memory");      \
  else if ((VMW) == 0) asm volatile("s_waitcnt vmcnt(0)" ::: "memory");      \
  __builtin_amdgcn_s_barrier();                                              \
  CFENCE;                                                                    \
  {                                                                          \
    const char* const bb = smem + ((S) & 3) * 32768;                         \
    i32x8 av[4], bv[4];                                                      \
    _Pragma("unroll") for (int mb = 0; mb < 4; ++mb)                         \
      LOAD6(av[mb], bb, adA0[mb], adA1[mb])                                  \
    _Pragma("unroll") for (int nb = 0; nb < 4; ++nb)                         \
      LOAD6(bv[nb], bb, adB0[nb], adB1[nb])                                  \
    if (STG) {                                                               \
      char* const sbf = smem + (((S) + 3) & 3) * 32768;                      \
      const size_t ko = (size_t)((S) + 3) * 16384;                           \
      _Pragma("unroll") for (int i = 0; i < 4; ++i) {                        \
        gl_lds16b(sAc + ko + i * 4096 + dd, sbf + i * 4096 + dd);            \
        gl_lds16b(sBc + ko + i * 4096 + dd, sbf + 16384 + i * 4096 + dd);    \
      }                                                                      \
    }                                                                        \
    _Pragma("unroll") for (int mb = 0; mb < 4; ++mb)                         \
      _Pragma("unroll") for (int nb = 0; nb < 4; ++nb)                       \
        acc[mb][nb] = __builtin_amdgcn_mfma_scale_f32_32x32x64_f8f6f4(       \
            av[mb], bv[nb], acc[mb][nb], 2 /*FP6*/, 2 /*FP6*/,               \
            0, 0x7F7F7F7F, 0, 0x7F7F7F7F);                                   \
  }                                                                          \
} while (0)

  // 128 K-chunks of 64; stage chunk S+3 in iters 0..124
  for (int s = 0; s < 124; s += 4) {
    ITER(s + 0, true, 16);
    ITER(s + 1, true, 16);
    ITER(s + 2, true, 16);
    ITER(s + 3, true, 16);
  }
  ITER(124, true, 16);    // stages chunk 127
  ITER(125, false, 16);
  ITER(126, false, 8);
  ITER(127, false, 0);

#undef ITER
#undef LOAD6

  // epilogue: 32x32 C/D map (verified R6/R9/R11): col = lane&31,
  // row = (reg&3) + 8*(reg>>2) + 4*(lane>>5)
  const int rb = bi * 256 + wr * 128;
  const int cb = bj * 256 + wc * 128;
#pragma unroll
  for (int mb = 0; mb < 4; ++mb) {
#pragma unroll
    for (int nb = 0; nb < 4; ++nb) {
      const int c = cb + nb * 32 + l31;
#pragma unroll
      for (int rg = 0; rg < 4; ++rg) {
        const int r0 = rb + mb * 32 + rg * 8 + hi * 4;
#pragma unroll
        for (int j = 0; j < 4; ++j)
          C[(size_t)(r0 + j) * N_DIM + c] = acc[mb][nb][rg * 4 + j];
      }
    }
  }
}

extern "C" void kernel_launch(void* const* d_in, const int* in_sizes, int n_in,
                              void* d_out, int out_size, void* d_ws, size_t ws_size,
                              hipStream_t stream) {
  const float* A = (const float*)d_in[0];
  float* C = (float*)d_out;
  unsigned char* At = (unsigned char*)d_ws;  // 32 MiB (16KB-padded fp6 chunks)

  transpose_pack_fp6<<<dim3((M_DIM / 64) * (N_DIM / 64)), 256, 0, stream>>>(A, At);
  gram_fp6<<<dim3(16 * 16), 256, 0, stream>>>(At, C);
}